// Round 9
// baseline (461.318 us; speedup 1.0000x reference)
//
#include <hip/hip_runtime.h>
#include <math.h>

#define NODES  50000
#define EDGES  800000
#define GRAPHS 256
#define FEAT   128
#define STATE  64
#define M_OUT  32
#define ROUNDS 4
#define NTILES (NODES / 16)            // 3125, exact
#define HALF   32                      // features per plane
#define PLANE  ((long)NODES * HALF)    // bf16 elements per plane (3.2 MB)
#define SCAN_BLOCKS ((NODES + 1023) / 1024)  // 49

typedef unsigned short bfraw;
typedef float v4f __attribute__((ext_vector_type(4)));
typedef unsigned short v4h __attribute__((ext_vector_type(4)));

__device__ __forceinline__ float bf2f(bfraw u) {
    union { unsigned int i; float f; } v; v.i = ((unsigned int)u) << 16; return v.f;
}
__device__ __forceinline__ bfraw f2bf(float f) {
    union { float f; unsigned int i; } v; v.f = f;
    unsigned int r = v.i + 0x7FFF + ((v.i >> 16) & 1); // round-nearest-even
    return (bfraw)(r >> 16);
}
__device__ __forceinline__ float4 nt_load4(const float* p) {
    v4f v = __builtin_nontemporal_load((const v4f*)p);
    return make_float4(v.x, v.y, v.z, v.w);
}
__device__ __forceinline__ void nt_store4(float* p, float4 v) {
    v4f t = {v.x, v.y, v.z, v.w};
    __builtin_nontemporal_store(t, (v4f*)p);
}
__device__ __forceinline__ void nt_store_bf4(bfraw* p, float a, float b, float c, float d) {
    v4h u = {f2bf(a), f2bf(b), f2bf(c), f2bf(d)};
    __builtin_nontemporal_store(u, (v4h*)p);
}

// ---------------------------------------------------------------------------
// 8-deep gather over one 3.2MB bf16 plane. csr reads are nontemporal (stream);
// plane reads stay cached (the L2-resident working set).
// ---------------------------------------------------------------------------
__device__ __forceinline__ float4 gather_sum8_p(const int* __restrict__ csr,
                                                const bfraw* __restrict__ plane,
                                                int beg, int end, int jg)
{
    float4 acc = make_float4(0.f, 0.f, 0.f, 0.f);
    for (int i = beg; i < end; i += 8) {
        int last = end - 1;
        int i1 = i + 1 < last ? i + 1 : last;
        int i2 = i + 2 < last ? i + 2 : last;
        int i3 = i + 3 < last ? i + 3 : last;
        int i4 = i + 4 < last ? i + 4 : last;
        int i5 = i + 5 < last ? i + 5 : last;
        int i6 = i + 6 < last ? i + 6 : last;
        int i7 = i + 7 < last ? i + 7 : last;
        int s0 = __builtin_nontemporal_load(csr + i);
        int s1 = __builtin_nontemporal_load(csr + i1);
        int s2 = __builtin_nontemporal_load(csr + i2);
        int s3 = __builtin_nontemporal_load(csr + i3);
        int s4 = __builtin_nontemporal_load(csr + i4);
        int s5 = __builtin_nontemporal_load(csr + i5);
        int s6 = __builtin_nontemporal_load(csr + i6);
        int s7 = __builtin_nontemporal_load(csr + i7);
        ushort4 v0 = *(const ushort4*)(plane + (long)s0 * HALF + jg);
        ushort4 v1 = *(const ushort4*)(plane + (long)s1 * HALF + jg);
        ushort4 v2 = *(const ushort4*)(plane + (long)s2 * HALF + jg);
        ushort4 v3 = *(const ushort4*)(plane + (long)s3 * HALF + jg);
        ushort4 v4 = *(const ushort4*)(plane + (long)s4 * HALF + jg);
        ushort4 v5 = *(const ushort4*)(plane + (long)s5 * HALF + jg);
        ushort4 v6 = *(const ushort4*)(plane + (long)s6 * HALF + jg);
        ushort4 v7 = *(const ushort4*)(plane + (long)s7 * HALF + jg);
        float m1 = (i + 1 < end) ? 1.f : 0.f;
        float m2 = (i + 2 < end) ? 1.f : 0.f;
        float m3 = (i + 3 < end) ? 1.f : 0.f;
        float m4 = (i + 4 < end) ? 1.f : 0.f;
        float m5 = (i + 5 < end) ? 1.f : 0.f;
        float m6 = (i + 6 < end) ? 1.f : 0.f;
        float m7 = (i + 7 < end) ? 1.f : 0.f;
        acc.x += bf2f(v0.x);      acc.y += bf2f(v0.y);      acc.z += bf2f(v0.z);      acc.w += bf2f(v0.w);
        acc.x += bf2f(v1.x) * m1; acc.y += bf2f(v1.y) * m1; acc.z += bf2f(v1.z) * m1; acc.w += bf2f(v1.w) * m1;
        acc.x += bf2f(v2.x) * m2; acc.y += bf2f(v2.y) * m2; acc.z += bf2f(v2.z) * m2; acc.w += bf2f(v2.w) * m2;
        acc.x += bf2f(v3.x) * m3; acc.y += bf2f(v3.y) * m3; acc.z += bf2f(v3.z) * m3; acc.w += bf2f(v3.w) * m3;
        acc.x += bf2f(v4.x) * m4; acc.y += bf2f(v4.y) * m4; acc.z += bf2f(v4.z) * m4; acc.w += bf2f(v4.w) * m4;
        acc.x += bf2f(v5.x) * m5; acc.y += bf2f(v5.y) * m5; acc.z += bf2f(v5.z) * m5; acc.w += bf2f(v5.w) * m5;
        acc.x += bf2f(v6.x) * m6; acc.y += bf2f(v6.y) * m6; acc.z += bf2f(v6.z) * m6; acc.w += bf2f(v6.w) * m6;
        acc.x += bf2f(v7.x) * m7; acc.y += bf2f(v7.y) * m7; acc.z += bf2f(v7.z) * m7; acc.w += bf2f(v7.w) * m7;
    }
    return acc;
}

// ---------------------------------------------------------------------------
// Plane gather: agg_half[n][0..31] = sum over edges of plane[src].
// 8 lanes/node, 32 nodes/block, no barriers/LDS. aggH store is nontemporal so
// the write stream doesn't evict the plane from L2.
// ---------------------------------------------------------------------------
__global__ __launch_bounds__(256) void k_gather_half(
    const int* __restrict__ rowptr, const int* __restrict__ csr,
    const bfraw* __restrict__ plane, float* __restrict__ agg_half)
{
    int n = blockIdx.x * 32 + (threadIdx.x >> 3);
    if (n >= NODES) return;
    int jg = (threadIdx.x & 7) << 2;
    int beg = rowptr[n], end = rowptr[n + 1];
    float4 acc = gather_sum8_p(csr, plane, beg, end, jg);
    nt_store4(agg_half + (long)n * HALF + jg, acc);
}

// ---------------------------------------------------------------------------
// Fused: state = relu(x @ inW + inb); msg planes = relu(state @ msgW + msgb).
// inW staged in TWO 16KB halves through one reused buffer: LDS 62->45KB,
// 2 -> 3 blocks/CU. x reads nontemporal (one-shot stream).
// ---------------------------------------------------------------------------
__global__ __launch_bounds__(256) void k_in_msg(
    const float* __restrict__ x, const float* __restrict__ inW, const float* __restrict__ inb,
    const float* __restrict__ msgW, const float* __restrict__ msgb,
    float* __restrict__ state, bfraw* __restrict__ msg0, bfraw* __restrict__ msg1)
{
    __shared__ float sInW[64 * STATE];      // 16 KB, holds one K-half at a time
    __shared__ float sMsgW[STATE * STATE];  // 16 KB
    __shared__ float sInb[STATE], sMsgb[STATE];
    __shared__ float sx[16 * 132];          // 8.45 KB
    __shared__ float ss[16 * 68];           // 4.35 KB

    const int ns = threadIdx.x >> 4;
    const int jg = (threadIdx.x & 15) << 2;
    const int base = blockIdx.x * 16;
    const int n = base + ns;

    // stage msgW, biases, x tile, and inW K-half 0
    for (int i = threadIdx.x; i < (STATE * STATE) / 4; i += 256)
        *(float4*)(sMsgW + i * 4) = *(const float4*)(msgW + i * 4);
    if (threadIdx.x < STATE) {
        sInb[threadIdx.x]  = inb[threadIdx.x];
        sMsgb[threadIdx.x] = msgb[threadIdx.x];
    }
    for (int i = threadIdx.x; i < 512; i += 256) {
        int row = i >> 5, q = (i & 31) << 2;
        *(float4*)(sx + row * 132 + q) = nt_load4(x + (long)(base + row) * FEAT + q);
    }
    for (int i = threadIdx.x; i < (64 * STATE) / 4; i += 256)
        *(float4*)(sInW + i * 4) = *(const float4*)(inW + i * 4);
    __syncthreads();

    float a0 = sInb[jg], a1 = sInb[jg + 1], a2 = sInb[jg + 2], a3 = sInb[jg + 3];
    const float* xr = sx + ns * 132;
    #pragma unroll 8
    for (int k = 0; k < 64; k++) {
        float xv = xr[k];
        float4 w = *(const float4*)(sInW + k * STATE + jg);
        a0 += xv * w.x; a1 += xv * w.y; a2 += xv * w.z; a3 += xv * w.w;
    }
    __syncthreads();
    // stage inW K-half 1
    for (int i = threadIdx.x; i < (64 * STATE) / 4; i += 256)
        *(float4*)(sInW + i * 4) = *(const float4*)(inW + 64 * STATE + i * 4);
    __syncthreads();
    #pragma unroll 8
    for (int k = 0; k < 64; k++) {
        float xv = xr[64 + k];
        float4 w = *(const float4*)(sInW + k * STATE + jg);
        a0 += xv * w.x; a1 += xv * w.y; a2 += xv * w.z; a3 += xv * w.w;
    }
    a0 = fmaxf(a0, 0.f); a1 = fmaxf(a1, 0.f); a2 = fmaxf(a2, 0.f); a3 = fmaxf(a3, 0.f);
    nt_store4(state + (long)n * STATE + jg, make_float4(a0, a1, a2, a3));
    *(float4*)(ss + ns * 68 + jg) = make_float4(a0, a1, a2, a3);
    __syncthreads();

    float m0 = sMsgb[jg], m1 = sMsgb[jg + 1], m2 = sMsgb[jg + 2], m3 = sMsgb[jg + 3];
    const float* sr = ss + ns * 68;
    #pragma unroll 8
    for (int k = 0; k < STATE; k++) {
        float sv = sr[k];
        float4 w = *(const float4*)(sMsgW + k * STATE + jg);
        m0 += sv * w.x; m1 += sv * w.y; m2 += sv * w.z; m3 += sv * w.w;
    }
    m0 = fmaxf(m0, 0.f); m1 = fmaxf(m1, 0.f); m2 = fmaxf(m2, 0.f); m3 = fmaxf(m3, 0.f);
    if (jg < HALF) nt_store_bf4(msg0 + (long)n * HALF + jg, m0, m1, m2, m3);
    else           nt_store_bf4(msg1 + (long)n * HALF + (jg - HALF), m0, m1, m2, m3);
}

// ---------------------------------------------------------------------------
// CSR build: histogram + hierarchical scan + fill (NT edge streams, NT csr store)
// ---------------------------------------------------------------------------
__global__ __launch_bounds__(256) void k_hist(const int* __restrict__ ei, int* __restrict__ deg)
{
    int e = blockIdx.x * 256 + threadIdx.x;
    if (e < EDGES) atomicAdd(&deg[__builtin_nontemporal_load(ei + EDGES + e)], 1);
}

__global__ __launch_bounds__(1024) void k_scan1(const int* __restrict__ deg,
                                                int* __restrict__ part, int* __restrict__ bsum)
{
    __shared__ int wsum[16];
    const int tid = threadIdx.x, lane = tid & 63, wid = tid >> 6;
    int n = blockIdx.x * 1024 + tid;
    int v = (n < NODES) ? deg[n] : 0;
    int incl = v;
    #pragma unroll
    for (int off = 1; off < 64; off <<= 1) {
        int t = __shfl_up(incl, off, 64);
        if (lane >= off) incl += t;
    }
    if (lane == 63) wsum[wid] = incl;
    __syncthreads();
    if (tid < 16) {
        int t = wsum[tid];
        #pragma unroll
        for (int off = 1; off < 16; off <<= 1) {
            int u = __shfl_up(t, off, 64);
            if (tid >= off) t += u;
        }
        wsum[tid] = t;
    }
    __syncthreads();
    int wbase = (wid == 0) ? 0 : wsum[wid - 1];
    if (n < NODES) part[n] = wbase + incl - v;
    if (tid == 0) bsum[blockIdx.x] = wsum[15];
}

__global__ __launch_bounds__(64) void k_scan2(const int* __restrict__ bsum, int* __restrict__ bcarry)
{
    int t = threadIdx.x;
    int v = (t < SCAN_BLOCKS) ? bsum[t] : 0;
    int incl = v;
    #pragma unroll
    for (int off = 1; off < 64; off <<= 1) {
        int u = __shfl_up(incl, off, 64);
        if (t >= off) incl += u;
    }
    if (t < SCAN_BLOCKS) bcarry[t] = incl - v;
}

__global__ __launch_bounds__(256) void k_scan3(const int* __restrict__ part,
                                               const int* __restrict__ bcarry,
                                               int* __restrict__ rowptr, int* __restrict__ cursor)
{
    int n = blockIdx.x * 256 + threadIdx.x;
    if (n < NODES) {
        int r = part[n] + bcarry[n >> 10];
        rowptr[n] = r; cursor[n] = r;
    }
    if (n == 0) rowptr[NODES] = EDGES;
}

__global__ __launch_bounds__(256) void k_fill(const int* __restrict__ ei,
                                              int* __restrict__ cursor,
                                              int* __restrict__ csr)
{
    int e = blockIdx.x * 256 + threadIdx.x;
    if (e < EDGES) {
        int src = __builtin_nontemporal_load(ei + e);
        int dst = __builtin_nontemporal_load(ei + EDGES + e);
        int slot = atomicAdd(&cursor[dst], 1);
        __builtin_nontemporal_store(src, csr + slot);
    }
}

// ---------------------------------------------------------------------------
// Streaming update + next-message (all streams nontemporal; weights in LDS).
// ---------------------------------------------------------------------------
__global__ __launch_bounds__(256) void k_upd_msg(
    const float* __restrict__ updW, const float* __restrict__ updb,
    const float* __restrict__ msgW, const float* __restrict__ msgb,
    const float* __restrict__ aggH0, const float* __restrict__ aggH1,
    float* __restrict__ state, bfraw* __restrict__ msg0, bfraw* __restrict__ msg1)
{
    __shared__ float sUpdW[STATE * STATE], sMsgW[STATE * STATE];
    __shared__ float sUpdb[STATE], sMsgb[STATE];
    __shared__ float sa[16 * 68], ss[16 * 68];

    for (int i = threadIdx.x; i < (STATE * STATE) / 4; i += 256) {
        *(float4*)(sUpdW + i * 4) = *(const float4*)(updW + i * 4);
        *(float4*)(sMsgW + i * 4) = *(const float4*)(msgW + i * 4);
    }
    if (threadIdx.x < STATE) {
        sUpdb[threadIdx.x] = updb[threadIdx.x];
        sMsgb[threadIdx.x] = msgb[threadIdx.x];
    }

    const int ns = threadIdx.x >> 4;
    const int jg = (threadIdx.x & 15) << 2;
    const int base = blockIdx.x * 16;
    const int n = base + ns;

    {
        int row = threadIdx.x >> 4, q = (threadIdx.x & 15) << 2;
        int nn = base + row;
        float4 v;
        if (q < HALF) v = nt_load4(aggH0 + (long)nn * HALF + q);
        else          v = nt_load4(aggH1 + (long)nn * HALF + (q - HALF));
        *(float4*)(sa + row * 68 + q) = v;
    }
    __syncthreads();

    float a0 = sUpdb[jg], a1 = sUpdb[jg + 1], a2 = sUpdb[jg + 2], a3 = sUpdb[jg + 3];
    const float* ar = sa + ns * 68;
    #pragma unroll 8
    for (int k = 0; k < STATE; k++) {
        float av = ar[k];
        float4 w = *(const float4*)(sUpdW + k * STATE + jg);
        a0 += av * w.x; a1 += av * w.y; a2 += av * w.z; a3 += av * w.w;
    }
    a0 = fmaxf(a0, 0.f); a1 = fmaxf(a1, 0.f); a2 = fmaxf(a2, 0.f); a3 = fmaxf(a3, 0.f);
    float4 st = nt_load4(state + (long)n * STATE + jg);
    float s0 = st.x + a0, s1 = st.y + a1, s2 = st.z + a2, s3 = st.w + a3;
    nt_store4(state + (long)n * STATE + jg, make_float4(s0, s1, s2, s3));
    *(float4*)(ss + ns * 68 + jg) = make_float4(s0, s1, s2, s3);
    __syncthreads();

    float m0 = sMsgb[jg], m1 = sMsgb[jg + 1], m2 = sMsgb[jg + 2], m3 = sMsgb[jg + 3];
    const float* sr = ss + ns * 68;
    #pragma unroll 8
    for (int k = 0; k < STATE; k++) {
        float sv = sr[k];
        float4 w = *(const float4*)(sMsgW + k * STATE + jg);
        m0 += sv * w.x; m1 += sv * w.y; m2 += sv * w.z; m3 += sv * w.w;
    }
    m0 = fmaxf(m0, 0.f); m1 = fmaxf(m1, 0.f); m2 = fmaxf(m2, 0.f); m3 = fmaxf(m3, 0.f);
    if (jg < HALF) nt_store_bf4(msg0 + (long)n * HALF + jg, m0, m1, m2, m3);
    else           nt_store_bf4(msg1 + (long)n * HALF + (jg - HALF), m0, m1, m2, m3);
}

// ---------------------------------------------------------------------------
// Last round: update + pooling with run-length reduction over sorted batch.
// ---------------------------------------------------------------------------
__global__ __launch_bounds__(256) void k_upd_pool(
    const float* __restrict__ updW, const float* __restrict__ updb,
    const float* __restrict__ aggH0, const float* __restrict__ aggH1,
    const float* __restrict__ state, const int* __restrict__ batch,
    float* __restrict__ gs)
{
    __shared__ float sUpdW[STATE * STATE];
    __shared__ float sUpdb[STATE];
    __shared__ float sa[16 * 68];
    __shared__ float ssum[16 * 68];
    __shared__ int   sg[16];

    for (int i = threadIdx.x; i < (STATE * STATE) / 4; i += 256)
        *(float4*)(sUpdW + i * 4) = *(const float4*)(updW + i * 4);
    if (threadIdx.x < STATE) sUpdb[threadIdx.x] = updb[threadIdx.x];

    const int ns = threadIdx.x >> 4;
    const int jg = (threadIdx.x & 15) << 2;
    const int base = blockIdx.x * 16;
    const int n = base + ns;

    {
        int row = threadIdx.x >> 4, q = (threadIdx.x & 15) << 2;
        int nn = base + row;
        float4 v;
        if (q < HALF) v = nt_load4(aggH0 + (long)nn * HALF + q);
        else          v = nt_load4(aggH1 + (long)nn * HALF + (q - HALF));
        *(float4*)(sa + row * 68 + q) = v;
    }
    if (threadIdx.x < 16) sg[threadIdx.x] = batch[base + threadIdx.x];
    __syncthreads();

    float a0 = sUpdb[jg], a1 = sUpdb[jg + 1], a2 = sUpdb[jg + 2], a3 = sUpdb[jg + 3];
    const float* ar = sa + ns * 68;
    #pragma unroll 8
    for (int k = 0; k < STATE; k++) {
        float av = ar[k];
        float4 w = *(const float4*)(sUpdW + k * STATE + jg);
        a0 += av * w.x; a1 += av * w.y; a2 += av * w.z; a3 += av * w.w;
    }
    a0 = fmaxf(a0, 0.f); a1 = fmaxf(a1, 0.f); a2 = fmaxf(a2, 0.f); a3 = fmaxf(a3, 0.f);
    float4 st = nt_load4(state + (long)n * STATE + jg);
    *(float4*)(ssum + ns * 68 + jg) = make_float4(st.x + a0, st.y + a1, st.z + a2, st.w + a3);
    __syncthreads();

    if (threadIdx.x < STATE) {
        const int f = threadIdx.x;
        float run = ssum[f];
        int g = sg[0];
        #pragma unroll
        for (int r = 1; r < 16; r++) {
            int g2 = sg[r];
            float v = ssum[r * 68 + f];
            if (g2 != g) {
                atomicAdd(&gs[g * STATE + f], run);
                run = v; g = g2;
            } else {
                run += v;
            }
        }
        atomicAdd(&gs[g * STATE + f], run);
    }
}

// ---------------------------------------------------------------------------
// mean = gs@meanW+b ; std = exp(0.5*clip(gs@lvW+b, -20, 2)) -> out[2,256,32]
// ---------------------------------------------------------------------------
__global__ __launch_bounds__(64) void k_final(
    const float* __restrict__ gs,
    const float* __restrict__ meanW, const float* __restrict__ meanb,
    const float* __restrict__ lvW, const float* __restrict__ lvb,
    float* __restrict__ out)
{
    __shared__ float row[STATE];
    const int g = blockIdx.x;
    const int j = threadIdx.x;
    row[j] = gs[g * STATE + j];
    __syncthreads();
    if (j < M_OUT) {
        float acc = meanb[j];
        #pragma unroll
        for (int k = 0; k < STATE; k++) acc += row[k] * meanW[k * M_OUT + j];
        out[g * M_OUT + j] = acc;
    } else {
        int jj = j - M_OUT;
        float acc = lvb[jj];
        #pragma unroll
        for (int k = 0; k < STATE; k++) acc += row[k] * lvW[k * M_OUT + jj];
        acc = fminf(fmaxf(acc, -20.f), 2.f);
        out[GRAPHS * M_OUT + g * M_OUT + jj] = expf(0.5f * acc);
    }
}

extern "C" void kernel_launch(void* const* d_in, const int* in_sizes, int n_in,
                              void* d_out, int out_size, void* d_ws, size_t ws_size,
                              hipStream_t stream) {
    const float* x     = (const float*)d_in[0];
    const int*   ei    = (const int*)d_in[1];   // [2, E]: row0 = src (gather), row1 = dst (scatter)
    const int*   batch = (const int*)d_in[2];
    const float* inW   = (const float*)d_in[3];
    const float* inb   = (const float*)d_in[4];
    const float* msgW  = (const float*)d_in[5]; // [4,64,64]
    const float* msgb  = (const float*)d_in[6]; // [4,64]
    const float* updW  = (const float*)d_in[7];
    const float* updb  = (const float*)d_in[8];
    const float* meanW = (const float*)d_in[9];
    const float* meanb = (const float*)d_in[10];
    const float* lvW   = (const float*)d_in[11];
    const float* lvb   = (const float*)d_in[12];
    float* out = (float*)d_out;

    const size_t NS   = (size_t)NODES * STATE * sizeof(float);  // 12.8 MB state
    const size_t PLB  = (size_t)PLANE * sizeof(bfraw);          //  3.2 MB per bf16 plane
    const size_t AGH  = (size_t)NODES * HALF * sizeof(float);   //  6.4 MB per agg half
    char* ws = (char*)d_ws;
    size_t off = 0;
    auto alloc = [&](size_t bytes) { void* p = ws + off; off += (bytes + 255) & ~(size_t)255; return p; };
    float* state  = (float*)alloc(NS);
    bfraw* msgA0  = (bfraw*)alloc(PLB);
    bfraw* msgA1  = (bfraw*)alloc(PLB);
    bfraw* msgB0  = (bfraw*)alloc(PLB);
    bfraw* msgB1  = (bfraw*)alloc(PLB);
    float* aggH0  = (float*)alloc(AGH);
    float* aggH1  = (float*)alloc(AGH);
    float* gs     = (float*)alloc((size_t)GRAPHS * STATE * sizeof(float));
    int*   deg    = (int*)alloc((size_t)NODES * sizeof(int));
    int*   part   = (int*)alloc((size_t)NODES * sizeof(int));
    int*   bsum   = (int*)alloc((size_t)SCAN_BLOCKS * sizeof(int));
    int*   bcarry = (int*)alloc((size_t)SCAN_BLOCKS * sizeof(int));
    int*   rowptr = (int*)alloc((size_t)(NODES + 1) * sizeof(int));
    int*   cursor = (int*)alloc((size_t)NODES * sizeof(int));
    int*   csr    = (int*)alloc((size_t)EDGES * sizeof(int));

    hipMemsetAsync(deg, 0, (size_t)NODES * sizeof(int), stream);
    hipMemsetAsync(gs, 0, (size_t)GRAPHS * STATE * sizeof(float), stream);

    k_hist<<<(EDGES + 255) / 256, 256, 0, stream>>>(ei, deg);
    k_scan1<<<SCAN_BLOCKS, 1024, 0, stream>>>(deg, part, bsum);
    k_scan2<<<1, 64, 0, stream>>>(bsum, bcarry);
    k_scan3<<<(NODES + 255) / 256, 256, 0, stream>>>(part, bcarry, rowptr, cursor);
    k_fill<<<(EDGES + 255) / 256, 256, 0, stream>>>(ei, cursor, csr);

    k_in_msg<<<NTILES, 256, 0, stream>>>(x, inW, inb, msgW, msgb, state, msgA0, msgA1);

    const int GG = (NODES + 31) / 32;
    bfraw *mi0 = msgA0, *mi1 = msgA1, *mo0 = msgB0, *mo1 = msgB1;
    for (int r = 0; r < ROUNDS; r++) {
        k_gather_half<<<GG, 256, 0, stream>>>(rowptr, csr, mi0, aggH0);
        k_gather_half<<<GG, 256, 0, stream>>>(rowptr, csr, mi1, aggH1);
        if (r < ROUNDS - 1) {
            k_upd_msg<<<NTILES, 256, 0, stream>>>(
                updW + r * STATE * STATE, updb + r * STATE,
                msgW + (r + 1) * STATE * STATE, msgb + (r + 1) * STATE,
                aggH0, aggH1, state, mo0, mo1);
            bfraw* t0 = mi0; mi0 = mo0; mo0 = t0;
            bfraw* t1 = mi1; mi1 = mo1; mo1 = t1;
        } else {
            k_upd_pool<<<NTILES, 256, 0, stream>>>(
                updW + r * STATE * STATE, updb + r * STATE,
                aggH0, aggH1, state, batch, gs);
        }
    }

    k_final<<<GRAPHS, 64, 0, stream>>>(gs, meanW, meanb, lvW, lvb, out);
}

// Round 10
// 403.908 us; speedup vs baseline: 1.1421x; 1.1421x over previous
//
#include <hip/hip_runtime.h>
#include <math.h>

#define NODES  50000
#define EDGES  800000
#define GRAPHS 256
#define FEAT   128
#define STATE  64
#define M_OUT  32
#define ROUNDS 4
#define NTILES (NODES / 16)            // 3125, exact
#define HALF   32                      // features per plane
#define PLANE  (50000L * 32L)          // bf16 elements per plane (3.2 MB)
#define SCAN_BLOCKS ((NODES + 1023) / 1024)  // 49
#define GG ((NODES + 31) / 32)         // gather grid: 1563

typedef unsigned short bfraw;

__device__ __forceinline__ float bf2f(bfraw u) {
    union { unsigned int i; float f; } v; v.i = ((unsigned int)u) << 16; return v.f;
}
__device__ __forceinline__ bfraw f2bf(float f) {
    union { float f; unsigned int i; } v; v.f = f;
    unsigned int r = v.i + 0x7FFF + ((v.i >> 16) & 1); // round-nearest-even
    return (bfraw)(r >> 16);
}
__device__ __forceinline__ void store_bf4(bfraw* p, float a, float b, float c, float d) {
    ushort4 u; u.x = f2bf(a); u.y = f2bf(b); u.z = f2bf(c); u.w = f2bf(d);
    *(ushort4*)p = u;
}

// ---------------------------------------------------------------------------
// 8-deep gather over one 3.2MB bf16 plane (plain cached loads).
// ---------------------------------------------------------------------------
__device__ __forceinline__ float4 gather_sum8_p(const int* __restrict__ csr,
                                                const bfraw* __restrict__ plane,
                                                int beg, int end, int jg)
{
    float4 acc = make_float4(0.f, 0.f, 0.f, 0.f);
    for (int i = beg; i < end; i += 8) {
        int last = end - 1;
        int i1 = i + 1 < last ? i + 1 : last;
        int i2 = i + 2 < last ? i + 2 : last;
        int i3 = i + 3 < last ? i + 3 : last;
        int i4 = i + 4 < last ? i + 4 : last;
        int i5 = i + 5 < last ? i + 5 : last;
        int i6 = i + 6 < last ? i + 6 : last;
        int i7 = i + 7 < last ? i + 7 : last;
        int s0 = csr[i],  s1 = csr[i1], s2 = csr[i2], s3 = csr[i3];
        int s4 = csr[i4], s5 = csr[i5], s6 = csr[i6], s7 = csr[i7];
        ushort4 v0 = *(const ushort4*)(plane + (long)s0 * HALF + jg);
        ushort4 v1 = *(const ushort4*)(plane + (long)s1 * HALF + jg);
        ushort4 v2 = *(const ushort4*)(plane + (long)s2 * HALF + jg);
        ushort4 v3 = *(const ushort4*)(plane + (long)s3 * HALF + jg);
        ushort4 v4 = *(const ushort4*)(plane + (long)s4 * HALF + jg);
        ushort4 v5 = *(const ushort4*)(plane + (long)s5 * HALF + jg);
        ushort4 v6 = *(const ushort4*)(plane + (long)s6 * HALF + jg);
        ushort4 v7 = *(const ushort4*)(plane + (long)s7 * HALF + jg);
        float m1 = (i + 1 < end) ? 1.f : 0.f;
        float m2 = (i + 2 < end) ? 1.f : 0.f;
        float m3 = (i + 3 < end) ? 1.f : 0.f;
        float m4 = (i + 4 < end) ? 1.f : 0.f;
        float m5 = (i + 5 < end) ? 1.f : 0.f;
        float m6 = (i + 6 < end) ? 1.f : 0.f;
        float m7 = (i + 7 < end) ? 1.f : 0.f;
        acc.x += bf2f(v0.x);      acc.y += bf2f(v0.y);      acc.z += bf2f(v0.z);      acc.w += bf2f(v0.w);
        acc.x += bf2f(v1.x) * m1; acc.y += bf2f(v1.y) * m1; acc.z += bf2f(v1.z) * m1; acc.w += bf2f(v1.w) * m1;
        acc.x += bf2f(v2.x) * m2; acc.y += bf2f(v2.y) * m2; acc.z += bf2f(v2.z) * m2; acc.w += bf2f(v2.w) * m2;
        acc.x += bf2f(v3.x) * m3; acc.y += bf2f(v3.y) * m3; acc.z += bf2f(v3.z) * m3; acc.w += bf2f(v3.w) * m3;
        acc.x += bf2f(v4.x) * m4; acc.y += bf2f(v4.y) * m4; acc.z += bf2f(v4.z) * m4; acc.w += bf2f(v4.w) * m4;
        acc.x += bf2f(v5.x) * m5; acc.y += bf2f(v5.y) * m5; acc.z += bf2f(v5.z) * m5; acc.w += bf2f(v5.w) * m5;
        acc.x += bf2f(v6.x) * m6; acc.y += bf2f(v6.y) * m6; acc.z += bf2f(v6.z) * m6; acc.w += bf2f(v6.w) * m6;
        acc.x += bf2f(v7.x) * m7; acc.y += bf2f(v7.y) * m7; acc.z += bf2f(v7.z) * m7; acc.w += bf2f(v7.w) * m7;
    }
    return acc;
}

// ---------------------------------------------------------------------------
// Plane gather with sequential pre-warm: each block streams a ~2KB slice of
// the plane (sequential HBM -> L3/L2 at streaming BW) before random gathers.
// 8 lanes/node, 32 nodes/block, no barriers/LDS.
// ---------------------------------------------------------------------------
__global__ __launch_bounds__(256) void k_gather_half(
    const int* __restrict__ rowptr, const int* __restrict__ csr,
    const bfraw* __restrict__ plane, float* __restrict__ agg_half)
{
    // pre-warm: slice of 1024 bf16 elems per block, 8 elems (16B) per thread
    float dummy = 0.f;
    {
        long s = (long)blockIdx.x * 1024 + (long)threadIdx.x * 8;
        if (threadIdx.x < 128 && s + 8 <= PLANE) {
            ushort4 a = *(const ushort4*)(plane + s);
            ushort4 b = *(const ushort4*)(plane + s + 4);
            dummy = bf2f(a.x) + bf2f(b.x);
        }
    }

    int n = blockIdx.x * 32 + (threadIdx.x >> 3);
    if (n >= NODES) return;
    int jg = (threadIdx.x & 7) << 2;
    int beg = rowptr[n], end = rowptr[n + 1];
    float4 acc = gather_sum8_p(csr, plane, beg, end, jg);
    if (dummy == 1e30f) acc.x += 1.f;   // keep pre-warm loads alive (never true)
    *(float4*)(agg_half + (long)n * HALF + jg) = acc;
}

// ---------------------------------------------------------------------------
// Fused: state = relu(x @ inW + inb); msg planes = relu(state @ msgW + msgb).
// ONE reused 16KB weight buffer (inW half0 -> inW half1 -> msgW):
// LDS ~29.6KB -> 5 blocks/CU.
// ---------------------------------------------------------------------------
__global__ __launch_bounds__(256) void k_in_msg(
    const float* __restrict__ x, const float* __restrict__ inW, const float* __restrict__ inb,
    const float* __restrict__ msgW, const float* __restrict__ msgb,
    float* __restrict__ state, bfraw* __restrict__ msg0, bfraw* __restrict__ msg1)
{
    __shared__ float sW[64 * STATE];        // 16 KB, reused 3x
    __shared__ float sInb[STATE], sMsgb[STATE];
    __shared__ float sx[16 * 132];          // 8.45 KB
    __shared__ float ss[16 * 68];           // 4.35 KB

    const int ns = threadIdx.x >> 4;
    const int jg = (threadIdx.x & 15) << 2;
    const int base = blockIdx.x * 16;
    const int n = base + ns;

    if (threadIdx.x < STATE) {
        sInb[threadIdx.x]  = inb[threadIdx.x];
        sMsgb[threadIdx.x] = msgb[threadIdx.x];
    }
    for (int i = threadIdx.x; i < 512; i += 256) {
        int row = i >> 5, q = (i & 31) << 2;
        *(float4*)(sx + row * 132 + q) = *(const float4*)(x + (long)(base + row) * FEAT + q);
    }
    for (int i = threadIdx.x; i < (64 * STATE) / 4; i += 256)
        *(float4*)(sW + i * 4) = *(const float4*)(inW + i * 4);
    __syncthreads();

    float a0 = sInb[jg], a1 = sInb[jg + 1], a2 = sInb[jg + 2], a3 = sInb[jg + 3];
    const float* xr = sx + ns * 132;
    #pragma unroll 8
    for (int k = 0; k < 64; k++) {
        float xv = xr[k];
        float4 w = *(const float4*)(sW + k * STATE + jg);
        a0 += xv * w.x; a1 += xv * w.y; a2 += xv * w.z; a3 += xv * w.w;
    }
    __syncthreads();
    for (int i = threadIdx.x; i < (64 * STATE) / 4; i += 256)
        *(float4*)(sW + i * 4) = *(const float4*)(inW + 64 * STATE + i * 4);
    __syncthreads();
    #pragma unroll 8
    for (int k = 0; k < 64; k++) {
        float xv = xr[64 + k];
        float4 w = *(const float4*)(sW + k * STATE + jg);
        a0 += xv * w.x; a1 += xv * w.y; a2 += xv * w.z; a3 += xv * w.w;
    }
    a0 = fmaxf(a0, 0.f); a1 = fmaxf(a1, 0.f); a2 = fmaxf(a2, 0.f); a3 = fmaxf(a3, 0.f);
    *(float4*)(state + (long)n * STATE + jg) = make_float4(a0, a1, a2, a3);
    *(float4*)(ss + ns * 68 + jg) = make_float4(a0, a1, a2, a3);
    __syncthreads();
    for (int i = threadIdx.x; i < (STATE * STATE) / 4; i += 256)
        *(float4*)(sW + i * 4) = *(const float4*)(msgW + i * 4);
    __syncthreads();

    float m0 = sMsgb[jg], m1 = sMsgb[jg + 1], m2 = sMsgb[jg + 2], m3 = sMsgb[jg + 3];
    const float* sr = ss + ns * 68;
    #pragma unroll 8
    for (int k = 0; k < STATE; k++) {
        float sv = sr[k];
        float4 w = *(const float4*)(sW + k * STATE + jg);
        m0 += sv * w.x; m1 += sv * w.y; m2 += sv * w.z; m3 += sv * w.w;
    }
    m0 = fmaxf(m0, 0.f); m1 = fmaxf(m1, 0.f); m2 = fmaxf(m2, 0.f); m3 = fmaxf(m3, 0.f);
    if (jg < HALF) store_bf4(msg0 + (long)n * HALF + jg, m0, m1, m2, m3);
    else           store_bf4(msg1 + (long)n * HALF + (jg - HALF), m0, m1, m2, m3);
}

// ---------------------------------------------------------------------------
// CSR build: histogram + hierarchical scan + fill (plain loads/stores)
// ---------------------------------------------------------------------------
__global__ __launch_bounds__(256) void k_hist(const int* __restrict__ ei, int* __restrict__ deg)
{
    int e = blockIdx.x * 256 + threadIdx.x;
    if (e < EDGES) atomicAdd(&deg[ei[EDGES + e]], 1);
}

__global__ __launch_bounds__(1024) void k_scan1(const int* __restrict__ deg,
                                                int* __restrict__ part, int* __restrict__ bsum)
{
    __shared__ int wsum[16];
    const int tid = threadIdx.x, lane = tid & 63, wid = tid >> 6;
    int n = blockIdx.x * 1024 + tid;
    int v = (n < NODES) ? deg[n] : 0;
    int incl = v;
    #pragma unroll
    for (int off = 1; off < 64; off <<= 1) {
        int t = __shfl_up(incl, off, 64);
        if (lane >= off) incl += t;
    }
    if (lane == 63) wsum[wid] = incl;
    __syncthreads();
    if (tid < 16) {
        int t = wsum[tid];
        #pragma unroll
        for (int off = 1; off < 16; off <<= 1) {
            int u = __shfl_up(t, off, 64);
            if (tid >= off) t += u;
        }
        wsum[tid] = t;
    }
    __syncthreads();
    int wbase = (wid == 0) ? 0 : wsum[wid - 1];
    if (n < NODES) part[n] = wbase + incl - v;
    if (tid == 0) bsum[blockIdx.x] = wsum[15];
}

__global__ __launch_bounds__(64) void k_scan2(const int* __restrict__ bsum, int* __restrict__ bcarry)
{
    int t = threadIdx.x;
    int v = (t < SCAN_BLOCKS) ? bsum[t] : 0;
    int incl = v;
    #pragma unroll
    for (int off = 1; off < 64; off <<= 1) {
        int u = __shfl_up(incl, off, 64);
        if (t >= off) incl += u;
    }
    if (t < SCAN_BLOCKS) bcarry[t] = incl - v;
}

__global__ __launch_bounds__(256) void k_scan3(const int* __restrict__ part,
                                               const int* __restrict__ bcarry,
                                               int* __restrict__ rowptr, int* __restrict__ cursor)
{
    int n = blockIdx.x * 256 + threadIdx.x;
    if (n < NODES) {
        int r = part[n] + bcarry[n >> 10];
        rowptr[n] = r; cursor[n] = r;
    }
    if (n == 0) rowptr[NODES] = EDGES;
}

__global__ __launch_bounds__(256) void k_fill(const int* __restrict__ ei,
                                              int* __restrict__ cursor,
                                              int* __restrict__ csr)
{
    int e = blockIdx.x * 256 + threadIdx.x;
    if (e < EDGES) {
        int src = ei[e];
        int dst = ei[EDGES + e];
        int slot = atomicAdd(&cursor[dst], 1);
        csr[slot] = src;
    }
}

// ---------------------------------------------------------------------------
// Streaming update + next-message (weights in LDS).
// ---------------------------------------------------------------------------
__global__ __launch_bounds__(256) void k_upd_msg(
    const float* __restrict__ updW, const float* __restrict__ updb,
    const float* __restrict__ msgW, const float* __restrict__ msgb,
    const float* __restrict__ aggH0, const float* __restrict__ aggH1,
    float* __restrict__ state, bfraw* __restrict__ msg0, bfraw* __restrict__ msg1)
{
    __shared__ float sUpdW[STATE * STATE], sMsgW[STATE * STATE];
    __shared__ float sUpdb[STATE], sMsgb[STATE];
    __shared__ float sa[16 * 68], ss[16 * 68];

    for (int i = threadIdx.x; i < (STATE * STATE) / 4; i += 256) {
        *(float4*)(sUpdW + i * 4) = *(const float4*)(updW + i * 4);
        *(float4*)(sMsgW + i * 4) = *(const float4*)(msgW + i * 4);
    }
    if (threadIdx.x < STATE) {
        sUpdb[threadIdx.x] = updb[threadIdx.x];
        sMsgb[threadIdx.x] = msgb[threadIdx.x];
    }

    const int ns = threadIdx.x >> 4;
    const int jg = (threadIdx.x & 15) << 2;
    const int base = blockIdx.x * 16;
    const int n = base + ns;

    {
        int row = threadIdx.x >> 4, q = (threadIdx.x & 15) << 2;
        int nn = base + row;
        float4 v;
        if (q < HALF) v = *(const float4*)(aggH0 + (long)nn * HALF + q);
        else          v = *(const float4*)(aggH1 + (long)nn * HALF + (q - HALF));
        *(float4*)(sa + row * 68 + q) = v;
    }
    __syncthreads();

    float a0 = sUpdb[jg], a1 = sUpdb[jg + 1], a2 = sUpdb[jg + 2], a3 = sUpdb[jg + 3];
    const float* ar = sa + ns * 68;
    #pragma unroll 8
    for (int k = 0; k < STATE; k++) {
        float av = ar[k];
        float4 w = *(const float4*)(sUpdW + k * STATE + jg);
        a0 += av * w.x; a1 += av * w.y; a2 += av * w.z; a3 += av * w.w;
    }
    a0 = fmaxf(a0, 0.f); a1 = fmaxf(a1, 0.f); a2 = fmaxf(a2, 0.f); a3 = fmaxf(a3, 0.f);
    float4 st = *(const float4*)(state + (long)n * STATE + jg);
    float s0 = st.x + a0, s1 = st.y + a1, s2 = st.z + a2, s3 = st.w + a3;
    *(float4*)(state + (long)n * STATE + jg) = make_float4(s0, s1, s2, s3);
    *(float4*)(ss + ns * 68 + jg) = make_float4(s0, s1, s2, s3);
    __syncthreads();

    float m0 = sMsgb[jg], m1 = sMsgb[jg + 1], m2 = sMsgb[jg + 2], m3 = sMsgb[jg + 3];
    const float* sr = ss + ns * 68;
    #pragma unroll 8
    for (int k = 0; k < STATE; k++) {
        float sv = sr[k];
        float4 w = *(const float4*)(sMsgW + k * STATE + jg);
        m0 += sv * w.x; m1 += sv * w.y; m2 += sv * w.z; m3 += sv * w.w;
    }
    m0 = fmaxf(m0, 0.f); m1 = fmaxf(m1, 0.f); m2 = fmaxf(m2, 0.f); m3 = fmaxf(m3, 0.f);
    if (jg < HALF) store_bf4(msg0 + (long)n * HALF + jg, m0, m1, m2, m3);
    else           store_bf4(msg1 + (long)n * HALF + (jg - HALF), m0, m1, m2, m3);
}

// ---------------------------------------------------------------------------
// Last round: update + pooling with run-length reduction over sorted batch.
// ---------------------------------------------------------------------------
__global__ __launch_bounds__(256) void k_upd_pool(
    const float* __restrict__ updW, const float* __restrict__ updb,
    const float* __restrict__ aggH0, const float* __restrict__ aggH1,
    const float* __restrict__ state, const int* __restrict__ batch,
    float* __restrict__ gs)
{
    __shared__ float sUpdW[STATE * STATE];
    __shared__ float sUpdb[STATE];
    __shared__ float sa[16 * 68];
    __shared__ float ssum[16 * 68];
    __shared__ int   sg[16];

    for (int i = threadIdx.x; i < (STATE * STATE) / 4; i += 256)
        *(float4*)(sUpdW + i * 4) = *(const float4*)(updW + i * 4);
    if (threadIdx.x < STATE) sUpdb[threadIdx.x] = updb[threadIdx.x];

    const int ns = threadIdx.x >> 4;
    const int jg = (threadIdx.x & 15) << 2;
    const int base = blockIdx.x * 16;
    const int n = base + ns;

    {
        int row = threadIdx.x >> 4, q = (threadIdx.x & 15) << 2;
        int nn = base + row;
        float4 v;
        if (q < HALF) v = *(const float4*)(aggH0 + (long)nn * HALF + q);
        else          v = *(const float4*)(aggH1 + (long)nn * HALF + (q - HALF));
        *(float4*)(sa + row * 68 + q) = v;
    }
    if (threadIdx.x < 16) sg[threadIdx.x] = batch[base + threadIdx.x];
    __syncthreads();

    float a0 = sUpdb[jg], a1 = sUpdb[jg + 1], a2 = sUpdb[jg + 2], a3 = sUpdb[jg + 3];
    const float* ar = sa + ns * 68;
    #pragma unroll 8
    for (int k = 0; k < STATE; k++) {
        float av = ar[k];
        float4 w = *(const float4*)(sUpdW + k * STATE + jg);
        a0 += av * w.x; a1 += av * w.y; a2 += av * w.z; a3 += av * w.w;
    }
    a0 = fmaxf(a0, 0.f); a1 = fmaxf(a1, 0.f); a2 = fmaxf(a2, 0.f); a3 = fmaxf(a3, 0.f);
    float4 st = *(const float4*)(state + (long)n * STATE + jg);
    *(float4*)(ssum + ns * 68 + jg) = make_float4(st.x + a0, st.y + a1, st.z + a2, st.w + a3);
    __syncthreads();

    if (threadIdx.x < STATE) {
        const int f = threadIdx.x;
        float run = ssum[f];
        int g = sg[0];
        #pragma unroll
        for (int r = 1; r < 16; r++) {
            int g2 = sg[r];
            float v = ssum[r * 68 + f];
            if (g2 != g) {
                atomicAdd(&gs[g * STATE + f], run);
                run = v; g = g2;
            } else {
                run += v;
            }
        }
        atomicAdd(&gs[g * STATE + f], run);
    }
}

// ---------------------------------------------------------------------------
// mean = gs@meanW+b ; std = exp(0.5*clip(gs@lvW+b, -20, 2)) -> out[2,256,32]
// ---------------------------------------------------------------------------
__global__ __launch_bounds__(64) void k_final(
    const float* __restrict__ gs,
    const float* __restrict__ meanW, const float* __restrict__ meanb,
    const float* __restrict__ lvW, const float* __restrict__ lvb,
    float* __restrict__ out)
{
    __shared__ float row[STATE];
    const int g = blockIdx.x;
    const int j = threadIdx.x;
    row[j] = gs[g * STATE + j];
    __syncthreads();
    if (j < M_OUT) {
        float acc = meanb[j];
        #pragma unroll
        for (int k = 0; k < STATE; k++) acc += row[k] * meanW[k * M_OUT + j];
        out[g * M_OUT + j] = acc;
    } else {
        int jj = j - M_OUT;
        float acc = lvb[jj];
        #pragma unroll
        for (int k = 0; k < STATE; k++) acc += row[k] * lvW[k * M_OUT + jj];
        acc = fminf(fmaxf(acc, -20.f), 2.f);
        out[GRAPHS * M_OUT + g * M_OUT + jj] = expf(0.5f * acc);
    }
}

extern "C" void kernel_launch(void* const* d_in, const int* in_sizes, int n_in,
                              void* d_out, int out_size, void* d_ws, size_t ws_size,
                              hipStream_t stream) {
    const float* x     = (const float*)d_in[0];
    const int*   ei    = (const int*)d_in[1];   // [2, E]: row0 = src (gather), row1 = dst (scatter)
    const int*   batch = (const int*)d_in[2];
    const float* inW   = (const float*)d_in[3];
    const float* inb   = (const float*)d_in[4];
    const float* msgW  = (const float*)d_in[5]; // [4,64,64]
    const float* msgb  = (const float*)d_in[6]; // [4,64]
    const float* updW  = (const float*)d_in[7];
    const float* updb  = (const float*)d_in[8];
    const float* meanW = (const float*)d_in[9];
    const float* meanb = (const float*)d_in[10];
    const float* lvW   = (const float*)d_in[11];
    const float* lvb   = (const float*)d_in[12];
    float* out = (float*)d_out;

    const size_t NS   = (size_t)NODES * STATE * sizeof(float);  // 12.8 MB state
    const size_t PLB  = (size_t)PLANE * sizeof(bfraw);          //  3.2 MB per bf16 plane
    const size_t AGH  = (size_t)NODES * HALF * sizeof(float);   //  6.4 MB per agg half
    char* ws = (char*)d_ws;
    size_t off = 0;
    auto alloc = [&](size_t bytes) { void* p = ws + off; off += (bytes + 255) & ~(size_t)255; return p; };
    float* state  = (float*)alloc(NS);
    bfraw* msgA0  = (bfraw*)alloc(PLB);
    bfraw* msgA1  = (bfraw*)alloc(PLB);
    bfraw* msgB0  = (bfraw*)alloc(PLB);
    bfraw* msgB1  = (bfraw*)alloc(PLB);
    float* aggH0  = (float*)alloc(AGH);
    float* aggH1  = (float*)alloc(AGH);
    float* gs     = (float*)alloc((size_t)GRAPHS * STATE * sizeof(float));
    int*   deg    = (int*)alloc((size_t)NODES * sizeof(int));
    int*   part   = (int*)alloc((size_t)NODES * sizeof(int));
    int*   bsum   = (int*)alloc((size_t)SCAN_BLOCKS * sizeof(int));
    int*   bcarry = (int*)alloc((size_t)SCAN_BLOCKS * sizeof(int));
    int*   rowptr = (int*)alloc((size_t)(NODES + 1) * sizeof(int));
    int*   cursor = (int*)alloc((size_t)NODES * sizeof(int));
    int*   csr    = (int*)alloc((size_t)EDGES * sizeof(int));

    hipMemsetAsync(deg, 0, (size_t)NODES * sizeof(int), stream);
    hipMemsetAsync(gs, 0, (size_t)GRAPHS * STATE * sizeof(float), stream);

    k_hist<<<(EDGES + 255) / 256, 256, 0, stream>>>(ei, deg);
    k_scan1<<<SCAN_BLOCKS, 1024, 0, stream>>>(deg, part, bsum);
    k_scan2<<<1, 64, 0, stream>>>(bsum, bcarry);
    k_scan3<<<(NODES + 255) / 256, 256, 0, stream>>>(part, bcarry, rowptr, cursor);
    k_fill<<<(EDGES + 255) / 256, 256, 0, stream>>>(ei, cursor, csr);

    k_in_msg<<<NTILES, 256, 0, stream>>>(x, inW, inb, msgW, msgb, state, msgA0, msgA1);

    bfraw *mi0 = msgA0, *mi1 = msgA1, *mo0 = msgB0, *mo1 = msgB1;
    for (int r = 0; r < ROUNDS; r++) {
        k_gather_half<<<GG, 256, 0, stream>>>(rowptr, csr, mi0, aggH0);
        k_gather_half<<<GG, 256, 0, stream>>>(rowptr, csr, mi1, aggH1);
        if (r < ROUNDS - 1) {
            k_upd_msg<<<NTILES, 256, 0, stream>>>(
                updW + r * STATE * STATE, updb + r * STATE,
                msgW + (r + 1) * STATE * STATE, msgb + (r + 1) * STATE,
                aggH0, aggH1, state, mo0, mo1);
            bfraw* t0 = mi0; mi0 = mo0; mo0 = t0;
            bfraw* t1 = mi1; mi1 = mo1; mo1 = t1;
        } else {
            k_upd_pool<<<NTILES, 256, 0, stream>>>(
                updW + r * STATE * STATE, updb + r * STATE,
                aggH0, aggH1, state, batch, gs);
        }
    }

    k_final<<<GRAPHS, 64, 0, stream>>>(gs, meanW, meanb, lvW, lvb, out);
}

// Round 11
// 390.682 us; speedup vs baseline: 1.1808x; 1.0339x over previous
//
#include <hip/hip_runtime.h>
#include <math.h>

#define NODES  50000
#define EDGES  800000
#define GRAPHS 256
#define FEAT   128
#define STATE  64
#define M_OUT  32
#define ROUNDS 4
#define NTILES (NODES / 16)            // 3125, exact
#define HBLK   ((EDGES + 255) / 256)   // 3125 hist blocks
#define HALF   32                      // features per plane
#define PLANE  (50000L * 32L)          // bf16 elements per plane (3.2 MB)
#define SCAN_BLOCKS ((NODES + 1023) / 1024)  // 49
#define GNODES 64                      // nodes per gather block (4 lanes/node)
#define GGRID  ((NODES + GNODES - 1) / GNODES) // 782

typedef unsigned short bfraw;

__device__ __forceinline__ float bf2f(bfraw u) {
    union { unsigned int i; float f; } v; v.i = ((unsigned int)u) << 16; return v.f;
}
__device__ __forceinline__ bfraw f2bf(float f) {
    union { float f; unsigned int i; } v; v.f = f;
    unsigned int r = v.i + 0x7FFF + ((v.i >> 16) & 1); // round-nearest-even
    return (bfraw)(r >> 16);
}
__device__ __forceinline__ void store_bf4(bfraw* p, float a, float b, float c, float d) {
    ushort4 u; u.x = f2bf(a); u.y = f2bf(b); u.z = f2bf(c); u.w = f2bf(d);
    *(ushort4*)p = u;
}
__device__ __forceinline__ int packbf(float lo, float hi) {
    return ((int)f2bf(hi) << 16) | (int)f2bf(lo);
}
// accumulate 8 bf16 packed in an int4 into acc[0..7], scaled by m
__device__ __forceinline__ void addv8(float* acc, int4 v, float m) {
    union { int i; float f; } t;
    t.i = v.x << 16;                  acc[0] += t.f * m;
    t.i = v.x & (int)0xffff0000;      acc[1] += t.f * m;
    t.i = v.y << 16;                  acc[2] += t.f * m;
    t.i = v.y & (int)0xffff0000;      acc[3] += t.f * m;
    t.i = v.z << 16;                  acc[4] += t.f * m;
    t.i = v.z & (int)0xffff0000;      acc[5] += t.f * m;
    t.i = v.w << 16;                  acc[6] += t.f * m;
    t.i = v.w & (int)0xffff0000;      acc[7] += t.f * m;
}

// ---------------------------------------------------------------------------
// Plane gather: 4 lanes/node, each lane covers 8 feats with one 16B load per
// edge; 8 edges in flight. csr is uint16. Output agg half is bf16 (fp32 acc,
// one final round). Pre-warm streams the plane sequentially into cache.
// ---------------------------------------------------------------------------
__global__ __launch_bounds__(256) void k_gather_half(
    const int* __restrict__ rowptr, const unsigned short* __restrict__ csr,
    const bfraw* __restrict__ plane, bfraw* __restrict__ agg_half)
{
    float dummy = 0.f;
    {
        long s = (long)blockIdx.x * 2048 + (long)threadIdx.x * 8;
        if (s + 8 <= PLANE) {
            int4 a = *(const int4*)(plane + s);
            union { int i; float f; } t; t.i = a.x << 16;
            dummy = t.f;   // finite (bf16-origin); folded below with *0.0f
        }
    }

    int n = blockIdx.x * GNODES + (threadIdx.x >> 2);
    if (n >= NODES) return;
    const int q = (threadIdx.x & 3) * 8;   // feature offset (8 feats/lane)
    int beg = rowptr[n], end = rowptr[n + 1];

    float acc[8] = {0.f, 0.f, 0.f, 0.f, 0.f, 0.f, 0.f, 0.f};
    for (int i = beg; i < end; i += 8) {
        int last = end - 1;
        int i1 = i + 1 < last ? i + 1 : last;
        int i2 = i + 2 < last ? i + 2 : last;
        int i3 = i + 3 < last ? i + 3 : last;
        int i4 = i + 4 < last ? i + 4 : last;
        int i5 = i + 5 < last ? i + 5 : last;
        int i6 = i + 6 < last ? i + 6 : last;
        int i7 = i + 7 < last ? i + 7 : last;
        int s0 = csr[i],  s1 = csr[i1], s2 = csr[i2], s3 = csr[i3];
        int s4 = csr[i4], s5 = csr[i5], s6 = csr[i6], s7 = csr[i7];
        int4 v0 = *(const int4*)(plane + (long)s0 * HALF + q);
        int4 v1 = *(const int4*)(plane + (long)s1 * HALF + q);
        int4 v2 = *(const int4*)(plane + (long)s2 * HALF + q);
        int4 v3 = *(const int4*)(plane + (long)s3 * HALF + q);
        int4 v4 = *(const int4*)(plane + (long)s4 * HALF + q);
        int4 v5 = *(const int4*)(plane + (long)s5 * HALF + q);
        int4 v6 = *(const int4*)(plane + (long)s6 * HALF + q);
        int4 v7 = *(const int4*)(plane + (long)s7 * HALF + q);
        float m1 = (i + 1 < end) ? 1.f : 0.f;
        float m2 = (i + 2 < end) ? 1.f : 0.f;
        float m3 = (i + 3 < end) ? 1.f : 0.f;
        float m4 = (i + 4 < end) ? 1.f : 0.f;
        float m5 = (i + 5 < end) ? 1.f : 0.f;
        float m6 = (i + 6 < end) ? 1.f : 0.f;
        float m7 = (i + 7 < end) ? 1.f : 0.f;
        addv8(acc, v0, 1.f); addv8(acc, v1, m1);
        addv8(acc, v2, m2);  addv8(acc, v3, m3);
        addv8(acc, v4, m4);  addv8(acc, v5, m5);
        addv8(acc, v6, m6);  addv8(acc, v7, m7);
    }
    acc[0] += dummy * 0.0f;   // keep pre-warm loads alive; exact no-op (dummy finite)

    int4 o;
    o.x = packbf(acc[0], acc[1]); o.y = packbf(acc[2], acc[3]);
    o.z = packbf(acc[4], acc[5]); o.w = packbf(acc[6], acc[7]);
    *(int4*)(agg_half + (long)n * HALF + q) = o;
}

// ---------------------------------------------------------------------------
// Fused kernel A: blocks [0,HBLK) do the dst histogram (NT edge stream);
// blocks [HBLK, HBLK+NTILES) do state = relu(x@inW+b), msg = relu(state@msgW+b).
// The two are independent -> overlap in one dispatch.
// ---------------------------------------------------------------------------
__global__ __launch_bounds__(256) void k_in_msg_hist(
    const float* __restrict__ x, const float* __restrict__ inW, const float* __restrict__ inb,
    const float* __restrict__ msgW, const float* __restrict__ msgb,
    float* __restrict__ state, bfraw* __restrict__ msg0, bfraw* __restrict__ msg1,
    const int* __restrict__ ei, int* __restrict__ deg)
{
    __shared__ float sW[64 * STATE];        // 16 KB, reused 3x
    __shared__ float sInb[STATE], sMsgb[STATE];
    __shared__ float sx[16 * 132];
    __shared__ float ss[16 * 68];

    if (blockIdx.x < HBLK) {
        int e = blockIdx.x * 256 + threadIdx.x;
        if (e < EDGES) atomicAdd(&deg[__builtin_nontemporal_load(ei + EDGES + e)], 1);
        return;
    }

    const int ns = threadIdx.x >> 4;
    const int jg = (threadIdx.x & 15) << 2;
    const int base = (blockIdx.x - HBLK) * 16;
    const int n = base + ns;

    if (threadIdx.x < STATE) {
        sInb[threadIdx.x]  = inb[threadIdx.x];
        sMsgb[threadIdx.x] = msgb[threadIdx.x];
    }
    for (int i = threadIdx.x; i < 512; i += 256) {
        int row = i >> 5, q = (i & 31) << 2;
        *(float4*)(sx + row * 132 + q) = *(const float4*)(x + (long)(base + row) * FEAT + q);
    }
    for (int i = threadIdx.x; i < (64 * STATE) / 4; i += 256)
        *(float4*)(sW + i * 4) = *(const float4*)(inW + i * 4);
    __syncthreads();

    float a0 = sInb[jg], a1 = sInb[jg + 1], a2 = sInb[jg + 2], a3 = sInb[jg + 3];
    const float* xr = sx + ns * 132;
    #pragma unroll 8
    for (int k = 0; k < 64; k++) {
        float xv = xr[k];
        float4 w = *(const float4*)(sW + k * STATE + jg);
        a0 += xv * w.x; a1 += xv * w.y; a2 += xv * w.z; a3 += xv * w.w;
    }
    __syncthreads();
    for (int i = threadIdx.x; i < (64 * STATE) / 4; i += 256)
        *(float4*)(sW + i * 4) = *(const float4*)(inW + 64 * STATE + i * 4);
    __syncthreads();
    #pragma unroll 8
    for (int k = 0; k < 64; k++) {
        float xv = xr[64 + k];
        float4 w = *(const float4*)(sW + k * STATE + jg);
        a0 += xv * w.x; a1 += xv * w.y; a2 += xv * w.z; a3 += xv * w.w;
    }
    a0 = fmaxf(a0, 0.f); a1 = fmaxf(a1, 0.f); a2 = fmaxf(a2, 0.f); a3 = fmaxf(a3, 0.f);
    *(float4*)(state + (long)n * STATE + jg) = make_float4(a0, a1, a2, a3);
    *(float4*)(ss + ns * 68 + jg) = make_float4(a0, a1, a2, a3);
    __syncthreads();
    for (int i = threadIdx.x; i < (STATE * STATE) / 4; i += 256)
        *(float4*)(sW + i * 4) = *(const float4*)(msgW + i * 4);
    __syncthreads();

    float m0 = sMsgb[jg], m1 = sMsgb[jg + 1], m2 = sMsgb[jg + 2], m3 = sMsgb[jg + 3];
    const float* sr = ss + ns * 68;
    #pragma unroll 8
    for (int k = 0; k < STATE; k++) {
        float sv = sr[k];
        float4 w = *(const float4*)(sW + k * STATE + jg);
        m0 += sv * w.x; m1 += sv * w.y; m2 += sv * w.z; m3 += sv * w.w;
    }
    m0 = fmaxf(m0, 0.f); m1 = fmaxf(m1, 0.f); m2 = fmaxf(m2, 0.f); m3 = fmaxf(m3, 0.f);
    if (jg < HALF) store_bf4(msg0 + (long)n * HALF + jg, m0, m1, m2, m3);
    else           store_bf4(msg1 + (long)n * HALF + (jg - HALF), m0, m1, m2, m3);
}

// ---------------------------------------------------------------------------
// Hierarchical scan + fill (csr as uint16; NT edge-stream loads in fill)
// ---------------------------------------------------------------------------
__global__ __launch_bounds__(1024) void k_scan1(const int* __restrict__ deg,
                                                int* __restrict__ part, int* __restrict__ bsum)
{
    __shared__ int wsum[16];
    const int tid = threadIdx.x, lane = tid & 63, wid = tid >> 6;
    int n = blockIdx.x * 1024 + tid;
    int v = (n < NODES) ? deg[n] : 0;
    int incl = v;
    #pragma unroll
    for (int off = 1; off < 64; off <<= 1) {
        int t = __shfl_up(incl, off, 64);
        if (lane >= off) incl += t;
    }
    if (lane == 63) wsum[wid] = incl;
    __syncthreads();
    if (tid < 16) {
        int t = wsum[tid];
        #pragma unroll
        for (int off = 1; off < 16; off <<= 1) {
            int u = __shfl_up(t, off, 64);
            if (tid >= off) t += u;
        }
        wsum[tid] = t;
    }
    __syncthreads();
    int wbase = (wid == 0) ? 0 : wsum[wid - 1];
    if (n < NODES) part[n] = wbase + incl - v;
    if (tid == 0) bsum[blockIdx.x] = wsum[15];
}

__global__ __launch_bounds__(64) void k_scan2(const int* __restrict__ bsum, int* __restrict__ bcarry)
{
    int t = threadIdx.x;
    int v = (t < SCAN_BLOCKS) ? bsum[t] : 0;
    int incl = v;
    #pragma unroll
    for (int off = 1; off < 64; off <<= 1) {
        int u = __shfl_up(incl, off, 64);
        if (t >= off) incl += u;
    }
    if (t < SCAN_BLOCKS) bcarry[t] = incl - v;
}

__global__ __launch_bounds__(256) void k_scan3(const int* __restrict__ part,
                                               const int* __restrict__ bcarry,
                                               int* __restrict__ rowptr, int* __restrict__ cursor)
{
    int n = blockIdx.x * 256 + threadIdx.x;
    if (n < NODES) {
        int r = part[n] + bcarry[n >> 10];
        rowptr[n] = r; cursor[n] = r;
    }
    if (n == 0) rowptr[NODES] = EDGES;
}

__global__ __launch_bounds__(256) void k_fill(const int* __restrict__ ei,
                                              int* __restrict__ cursor,
                                              unsigned short* __restrict__ csr)
{
    int e = blockIdx.x * 256 + threadIdx.x;
    if (e < EDGES) {
        int src = __builtin_nontemporal_load(ei + e);
        int dst = __builtin_nontemporal_load(ei + EDGES + e);
        int slot = atomicAdd(&cursor[dst], 1);
        csr[slot] = (unsigned short)src;
    }
}

// ---------------------------------------------------------------------------
// Streaming update + next-message (agg halves are bf16 now).
// ---------------------------------------------------------------------------
__global__ __launch_bounds__(256) void k_upd_msg(
    const float* __restrict__ updW, const float* __restrict__ updb,
    const float* __restrict__ msgW, const float* __restrict__ msgb,
    const bfraw* __restrict__ aggH0, const bfraw* __restrict__ aggH1,
    float* __restrict__ state, bfraw* __restrict__ msg0, bfraw* __restrict__ msg1)
{
    __shared__ float sUpdW[STATE * STATE], sMsgW[STATE * STATE];
    __shared__ float sUpdb[STATE], sMsgb[STATE];
    __shared__ float sa[16 * 68], ss[16 * 68];

    for (int i = threadIdx.x; i < (STATE * STATE) / 4; i += 256) {
        *(float4*)(sUpdW + i * 4) = *(const float4*)(updW + i * 4);
        *(float4*)(sMsgW + i * 4) = *(const float4*)(msgW + i * 4);
    }
    if (threadIdx.x < STATE) {
        sUpdb[threadIdx.x] = updb[threadIdx.x];
        sMsgb[threadIdx.x] = msgb[threadIdx.x];
    }

    const int ns = threadIdx.x >> 4;
    const int jg = (threadIdx.x & 15) << 2;
    const int base = blockIdx.x * 16;
    const int n = base + ns;

    {
        int row = threadIdx.x >> 4, q = (threadIdx.x & 15) << 2;
        int nn = base + row;
        ushort4 u = (q < HALF) ? *(const ushort4*)(aggH0 + (long)nn * HALF + q)
                               : *(const ushort4*)(aggH1 + (long)nn * HALF + (q - HALF));
        float* d = sa + row * 68 + q;
        d[0] = bf2f(u.x); d[1] = bf2f(u.y); d[2] = bf2f(u.z); d[3] = bf2f(u.w);
    }
    __syncthreads();

    float a0 = sUpdb[jg], a1 = sUpdb[jg + 1], a2 = sUpdb[jg + 2], a3 = sUpdb[jg + 3];
    const float* ar = sa + ns * 68;
    #pragma unroll 8
    for (int k = 0; k < STATE; k++) {
        float av = ar[k];
        float4 w = *(const float4*)(sUpdW + k * STATE + jg);
        a0 += av * w.x; a1 += av * w.y; a2 += av * w.z; a3 += av * w.w;
    }
    a0 = fmaxf(a0, 0.f); a1 = fmaxf(a1, 0.f); a2 = fmaxf(a2, 0.f); a3 = fmaxf(a3, 0.f);
    float4 st = *(const float4*)(state + (long)n * STATE + jg);
    float s0 = st.x + a0, s1 = st.y + a1, s2 = st.z + a2, s3 = st.w + a3;
    *(float4*)(state + (long)n * STATE + jg) = make_float4(s0, s1, s2, s3);
    *(float4*)(ss + ns * 68 + jg) = make_float4(s0, s1, s2, s3);
    __syncthreads();

    float m0 = sMsgb[jg], m1 = sMsgb[jg + 1], m2 = sMsgb[jg + 2], m3 = sMsgb[jg + 3];
    const float* sr = ss + ns * 68;
    #pragma unroll 8
    for (int k = 0; k < STATE; k++) {
        float sv = sr[k];
        float4 w = *(const float4*)(sMsgW + k * STATE + jg);
        m0 += sv * w.x; m1 += sv * w.y; m2 += sv * w.z; m3 += sv * w.w;
    }
    m0 = fmaxf(m0, 0.f); m1 = fmaxf(m1, 0.f); m2 = fmaxf(m2, 0.f); m3 = fmaxf(m3, 0.f);
    if (jg < HALF) store_bf4(msg0 + (long)n * HALF + jg, m0, m1, m2, m3);
    else           store_bf4(msg1 + (long)n * HALF + (jg - HALF), m0, m1, m2, m3);
}

// ---------------------------------------------------------------------------
// Last round: update + pooling with run-length reduction over sorted batch.
// ---------------------------------------------------------------------------
__global__ __launch_bounds__(256) void k_upd_pool(
    const float* __restrict__ updW, const float* __restrict__ updb,
    const bfraw* __restrict__ aggH0, const bfraw* __restrict__ aggH1,
    const float* __restrict__ state, const int* __restrict__ batch,
    float* __restrict__ gs)
{
    __shared__ float sUpdW[STATE * STATE];
    __shared__ float sUpdb[STATE];
    __shared__ float sa[16 * 68];
    __shared__ float ssum[16 * 68];
    __shared__ int   sg[16];

    for (int i = threadIdx.x; i < (STATE * STATE) / 4; i += 256)
        *(float4*)(sUpdW + i * 4) = *(const float4*)(updW + i * 4);
    if (threadIdx.x < STATE) sUpdb[threadIdx.x] = updb[threadIdx.x];

    const int ns = threadIdx.x >> 4;
    const int jg = (threadIdx.x & 15) << 2;
    const int base = blockIdx.x * 16;
    const int n = base + ns;

    {
        int row = threadIdx.x >> 4, q = (threadIdx.x & 15) << 2;
        int nn = base + row;
        ushort4 u = (q < HALF) ? *(const ushort4*)(aggH0 + (long)nn * HALF + q)
                               : *(const ushort4*)(aggH1 + (long)nn * HALF + (q - HALF));
        float* d = sa + row * 68 + q;
        d[0] = bf2f(u.x); d[1] = bf2f(u.y); d[2] = bf2f(u.z); d[3] = bf2f(u.w);
    }
    if (threadIdx.x < 16) sg[threadIdx.x] = batch[base + threadIdx.x];
    __syncthreads();

    float a0 = sUpdb[jg], a1 = sUpdb[jg + 1], a2 = sUpdb[jg + 2], a3 = sUpdb[jg + 3];
    const float* ar = sa + ns * 68;
    #pragma unroll 8
    for (int k = 0; k < STATE; k++) {
        float av = ar[k];
        float4 w = *(const float4*)(sUpdW + k * STATE + jg);
        a0 += av * w.x; a1 += av * w.y; a2 += av * w.z; a3 += av * w.w;
    }
    a0 = fmaxf(a0, 0.f); a1 = fmaxf(a1, 0.f); a2 = fmaxf(a2, 0.f); a3 = fmaxf(a3, 0.f);
    float4 st = *(const float4*)(state + (long)n * STATE + jg);
    *(float4*)(ssum + ns * 68 + jg) = make_float4(st.x + a0, st.y + a1, st.z + a2, st.w + a3);
    __syncthreads();

    if (threadIdx.x < STATE) {
        const int f = threadIdx.x;
        float run = ssum[f];
        int g = sg[0];
        #pragma unroll
        for (int r = 1; r < 16; r++) {
            int g2 = sg[r];
            float v = ssum[r * 68 + f];
            if (g2 != g) {
                atomicAdd(&gs[g * STATE + f], run);
                run = v; g = g2;
            } else {
                run += v;
            }
        }
        atomicAdd(&gs[g * STATE + f], run);
    }
}

// ---------------------------------------------------------------------------
// mean = gs@meanW+b ; std = exp(0.5*clip(gs@lvW+b, -20, 2)) -> out[2,256,32]
// ---------------------------------------------------------------------------
__global__ __launch_bounds__(64) void k_final(
    const float* __restrict__ gs,
    const float* __restrict__ meanW, const float* __restrict__ meanb,
    const float* __restrict__ lvW, const float* __restrict__ lvb,
    float* __restrict__ out)
{
    __shared__ float row[STATE];
    const int g = blockIdx.x;
    const int j = threadIdx.x;
    row[j] = gs[g * STATE + j];
    __syncthreads();
    if (j < M_OUT) {
        float acc = meanb[j];
        #pragma unroll
        for (int k = 0; k < STATE; k++) acc += row[k] * meanW[k * M_OUT + j];
        out[g * M_OUT + j] = acc;
    } else {
        int jj = j - M_OUT;
        float acc = lvb[jj];
        #pragma unroll
        for (int k = 0; k < STATE; k++) acc += row[k] * lvW[k * M_OUT + jj];
        acc = fminf(fmaxf(acc, -20.f), 2.f);
        out[GRAPHS * M_OUT + g * M_OUT + jj] = expf(0.5f * acc);
    }
}

extern "C" void kernel_launch(void* const* d_in, const int* in_sizes, int n_in,
                              void* d_out, int out_size, void* d_ws, size_t ws_size,
                              hipStream_t stream) {
    const float* x     = (const float*)d_in[0];
    const int*   ei    = (const int*)d_in[1];   // [2, E]: row0 = src (gather), row1 = dst (scatter)
    const int*   batch = (const int*)d_in[2];
    const float* inW   = (const float*)d_in[3];
    const float* inb   = (const float*)d_in[4];
    const float* msgW  = (const float*)d_in[5]; // [4,64,64]
    const float* msgb  = (const float*)d_in[6]; // [4,64]
    const float* updW  = (const float*)d_in[7];
    const float* updb  = (const float*)d_in[8];
    const float* meanW = (const float*)d_in[9];
    const float* meanb = (const float*)d_in[10];
    const float* lvW   = (const float*)d_in[11];
    const float* lvb   = (const float*)d_in[12];
    float* out = (float*)d_out;

    const size_t NS   = (size_t)NODES * STATE * sizeof(float);  // 12.8 MB state
    const size_t PLB  = (size_t)PLANE * sizeof(bfraw);          //  3.2 MB per bf16 plane
    const size_t AGH  = (size_t)NODES * HALF * sizeof(bfraw);   //  3.2 MB per bf16 agg half
    char* ws = (char*)d_ws;
    size_t off = 0;
    auto alloc = [&](size_t bytes) { void* p = ws + off; off += (bytes + 255) & ~(size_t)255; return p; };
    float* state  = (float*)alloc(NS);
    bfraw* msgA0  = (bfraw*)alloc(PLB);
    bfraw* msgA1  = (bfraw*)alloc(PLB);
    bfraw* msgB0  = (bfraw*)alloc(PLB);
    bfraw* msgB1  = (bfraw*)alloc(PLB);
    bfraw* aggH0  = (bfraw*)alloc(AGH);
    bfraw* aggH1  = (bfraw*)alloc(AGH);
    float* gs     = (float*)alloc((size_t)GRAPHS * STATE * sizeof(float));
    int*   deg    = (int*)alloc((size_t)NODES * sizeof(int));
    int*   part   = (int*)alloc((size_t)NODES * sizeof(int));
    int*   bsum   = (int*)alloc((size_t)SCAN_BLOCKS * sizeof(int));
    int*   bcarry = (int*)alloc((size_t)SCAN_BLOCKS * sizeof(int));
    int*   rowptr = (int*)alloc((size_t)(NODES + 1) * sizeof(int));
    int*   cursor = (int*)alloc((size_t)NODES * sizeof(int));
    unsigned short* csr = (unsigned short*)alloc((size_t)EDGES * sizeof(unsigned short));

    hipMemsetAsync(deg, 0, (size_t)NODES * sizeof(int), stream);
    hipMemsetAsync(gs, 0, (size_t)GRAPHS * STATE * sizeof(float), stream);

    // fused: hist (blocks 0..HBLK) + input/message GEMM (blocks HBLK..HBLK+NTILES)
    k_in_msg_hist<<<HBLK + NTILES, 256, 0, stream>>>(
        x, inW, inb, msgW, msgb, state, msgA0, msgA1, ei, deg);

    k_scan1<<<SCAN_BLOCKS, 1024, 0, stream>>>(deg, part, bsum);
    k_scan2<<<1, 64, 0, stream>>>(bsum, bcarry);
    k_scan3<<<(NODES + 255) / 256, 256, 0, stream>>>(part, bcarry, rowptr, cursor);
    k_fill<<<(EDGES + 255) / 256, 256, 0, stream>>>(ei, cursor, csr);

    bfraw *mi0 = msgA0, *mi1 = msgA1, *mo0 = msgB0, *mo1 = msgB1;
    for (int r = 0; r < ROUNDS; r++) {
        k_gather_half<<<GGRID, 256, 0, stream>>>(rowptr, csr, mi0, aggH0);
        k_gather_half<<<GGRID, 256, 0, stream>>>(rowptr, csr, mi1, aggH1);
        if (r < ROUNDS - 1) {
            k_upd_msg<<<NTILES, 256, 0, stream>>>(
                updW + r * STATE * STATE, updb + r * STATE,
                msgW + (r + 1) * STATE * STATE, msgb + (r + 1) * STATE,
                aggH0, aggH1, state, mo0, mo1);
            bfraw* t0 = mi0; mi0 = mo0; mo0 = t0;
            bfraw* t1 = mi1; mi1 = mo1; mo1 = t1;
        } else {
            k_upd_pool<<<NTILES, 256, 0, stream>>>(
                updW + r * STATE * STATE, updb + r * STATE,
                aggH0, aggH1, state, batch, gs);
        }
    }

    k_final<<<GRAPHS, 64, 0, stream>>>(gs, meanW, meanb, lvW, lvb, out);
}